// Round 1
// baseline (1001.692 us; speedup 1.0000x reference)
//
#include <hip/hip_runtime.h>

#define N_ROWS 16384
#define CDIM 256
#define KDIM 8192
#define QSIZE 4194304           // 16*256*32*32
#define DIFF_OFF 4194304
#define EIND_OFF 4194305
#define PERP_OFF 4210689

// ---------------- ws layout (bytes) ----------------
// best   u64[16384]  @ 0        (131072)
// ee     f32[8192]   @ 131072   (32768)
// Fv     f32[16384]  @ 163840   (65536)
// ind    i32[16384]  @ 229376   (65536)
// counts i32[8192]   @ 294912   (32768)
// dpart  f32[1024]   @ 327680   (4096)

// ||e_k||^2, replicating np.sum(e*e, axis=0): sequential over c, separate
// square+add roundings (no FMA contraction).
__global__ __launch_bounds__(256) void k_ee(const float* __restrict__ e,
                                            float* __restrict__ ee) {
#pragma clang fp contract(off)
  int k = blockIdx.x * 256 + threadIdx.x;
  float s = 0.0f;
  for (int c = 0; c < CDIM; ++c) {
    float v = e[(size_t)c * KDIM + k];
    float sq = v * v;
    s = s + sq;
  }
  ee[k] = s;
}

// ||f_n||^2, replicating numpy pairwise_sum for n=256:
// P128(a[0:128]) + P128(a[128:256]), each P128 = 8-accumulator unrolled loop
// combined as ((r0+r1)+(r2+r3)) + ((r4+r5)+(r6+r7)).
__global__ __launch_bounds__(256) void k_ff(const float* __restrict__ x,
                                            float* __restrict__ Fv) {
#pragma clang fp contract(off)
  int n = blockIdx.x * 256 + threadIdx.x;
  int b = n >> 10, hw = n & 1023;
  const float* px = x + ((size_t)b << 18) + hw;  // x[b, c, hw] stride 1024 in c
  float sblk[2];
#pragma unroll
  for (int blk = 0; blk < 2; ++blk) {
    float r[8];
#pragma unroll
    for (int j = 0; j < 8; ++j) {
      float v = px[(size_t)(blk * 128 + j) << 10];
      r[j] = v * v;
    }
    for (int i = 8; i < 128; i += 8) {
#pragma unroll
      for (int j = 0; j < 8; ++j) {
        float v = px[(size_t)(blk * 128 + i + j) << 10];
        float sq = v * v;
        r[j] = r[j] + sq;
      }
    }
    sblk[blk] = ((r[0] + r[1]) + (r[2] + r[3])) + ((r[4] + r[5]) + (r[6] + r[7]));
  }
  Fv[n] = sblk[0] + sblk[1];
}

// Fused distance GEMM + argmin. 128 rows x 4096 cols per WG (grid 2 x 128).
// dot accumulated by a single sequential fp32 FMA chain over c=0..255
// (bit-matches BLAS sgemm microkernel). d = fl(fl(F - 2*dot) + ee).
// (dist,idx) packed into u64: ordered-float key in high 32 bits, index low,
// so min() == (smaller dist, then smaller index) — matches np.argmin ties.
__global__ __launch_bounds__(256) void k_main(const float* __restrict__ x,
                                              const float* __restrict__ e,
                                              const float* __restrict__ Fv,
                                              const float* __restrict__ ee,
                                              unsigned long long* __restrict__ best) {
  __shared__ __align__(16) float As[32][132];  // A[c][m], padded
  __shared__ __align__(16) float Bs[32][132];  // B[c][k], padded
  __shared__ unsigned long long red[128][16];

  const int tid = threadIdx.x;
  const int tx = tid & 15;        // 16 col groups * 8 cols
  const int ty = tid >> 4;        // 16 row groups * 8 rows
  const int row0 = blockIdx.y * 128;
  const int b = row0 >> 10;
  const int hw0 = row0 & 1023;
  const int k0base = blockIdx.x * 4096;

  float Freg[8];
#pragma unroll
  for (int i = 0; i < 8; ++i) Freg[i] = Fv[row0 + ty * 8 + i];

  unsigned long long bestreg[8];
#pragma unroll
  for (int i = 0; i < 8; ++i) bestreg[i] = 0xFFFFFFFFFFFFFFFFull;

  for (int kt = 0; kt < 32; ++kt) {
    const int k0 = k0base + kt * 128;
    float acc[8][8];
#pragma unroll
    for (int i = 0; i < 8; ++i)
#pragma unroll
      for (int j = 0; j < 8; ++j) acc[i][j] = 0.0f;

    for (int cc = 0; cc < 8; ++cc) {
      const int c0 = cc * 32;
      // stage A (32c x 128m) and B (32c x 128k): 4 float4 each per thread
#pragma unroll
      for (int p = 0; p < 4; ++p) {
        int slot = tid + p * 256;        // 0..1023
        int c = slot >> 5;               // 0..31
        int m4 = (slot & 31) << 2;       // 0..124
        float4 av = *(const float4*)(x + (((size_t)(b * 256 + c0 + c)) << 10) + hw0 + m4);
        *(float4*)&As[c][m4] = av;
        float4 bv = *(const float4*)(e + (size_t)(c0 + c) * KDIM + k0 + m4);
        *(float4*)&Bs[c][m4] = bv;
      }
      __syncthreads();
#pragma unroll
      for (int c = 0; c < 32; ++c) {
        float4 A0 = *(const float4*)&As[c][ty * 8];
        float4 A1 = *(const float4*)&As[c][ty * 8 + 4];
        float4 B0 = *(const float4*)&Bs[c][tx * 8];
        float4 B1 = *(const float4*)&Bs[c][tx * 8 + 4];
        float av[8] = {A0.x, A0.y, A0.z, A0.w, A1.x, A1.y, A1.z, A1.w};
        float bv[8] = {B0.x, B0.y, B0.z, B0.w, B1.x, B1.y, B1.z, B1.w};
#pragma unroll
        for (int i = 0; i < 8; ++i)
#pragma unroll
          for (int j = 0; j < 8; ++j)
            acc[i][j] = fmaf(av[i], bv[j], acc[i][j]);
      }
      __syncthreads();
    }
    // epilogue: distances + running argmin
#pragma unroll
    for (int i = 0; i < 8; ++i) {
#pragma unroll
      for (int j = 0; j < 8; ++j) {
        int k = k0 + tx * 8 + j;
        float t = fmaf(-2.0f, acc[i][j], Freg[i]);  // == fl(F - 2*dot), 2*dot exact
        float d = t + ee[k];
        unsigned key = __float_as_uint(d);
        key = (key & 0x80000000u) ? ~key : (key | 0x80000000u);
        unsigned long long pk = ((unsigned long long)key << 32) | (unsigned)k;
        if (pk < bestreg[i]) bestreg[i] = pk;
      }
    }
  }

  __syncthreads();
#pragma unroll
  for (int i = 0; i < 8; ++i) red[ty * 8 + i][tx] = bestreg[i];
  __syncthreads();
  if (tid < 128) {
    unsigned long long m = red[tid][0];
#pragma unroll
    for (int t = 1; t < 16; ++t) {
      unsigned long long v = red[tid][t];
      if (v < m) m = v;
    }
    atomicMin(&best[row0 + tid], m);
  }
}

__global__ __launch_bounds__(256) void k_ind(const unsigned long long* __restrict__ best,
                                             int* __restrict__ ind,
                                             int* __restrict__ counts,
                                             float* __restrict__ out) {
  int n = blockIdx.x * 256 + threadIdx.x;
  unsigned idx = (unsigned)(best[n] & 0xFFFFFFFFull);
  ind[n] = (int)idx;
  out[EIND_OFF + n] = (float)idx;
  atomicAdd(&counts[idx], 1);
}

// quantize (straight-through, replicating fl(x + fl(q - x))) + diff partials
__global__ __launch_bounds__(256) void k_out(const float* __restrict__ x,
                                             const float* __restrict__ e,
                                             const int* __restrict__ ind,
                                             float* __restrict__ out,
                                             float* __restrict__ dpart) {
  __shared__ float sd[256];
  int tid = threadIdx.x;
  float local = 0.0f;
  for (size_t i = (size_t)blockIdx.x * 256 + tid; i < QSIZE; i += (size_t)gridDim.x * 256) {
    int hw = (int)(i & 1023);
    int c = (int)((i >> 10) & 255);
    int b = (int)(i >> 18);
    int n = (b << 10) + hw;
    float xv = x[i];
    float q = e[(size_t)c * KDIM + ind[n]];
    float qd = q - xv;
    out[i] = xv + qd;
    local += qd * qd;
  }
  sd[tid] = local;
  __syncthreads();
  for (int s = 128; s > 0; s >>= 1) {
    if (tid < s) sd[tid] += sd[tid + s];
    __syncthreads();
  }
  if (tid == 0) dpart[blockIdx.x] = sd[0];
}

__global__ __launch_bounds__(256) void k_perp(const int* __restrict__ counts,
                                              const float* __restrict__ dpart,
                                              float* __restrict__ out) {
  __shared__ float sd[256];
  int tid = threadIdx.x;
  float s = 0.0f;
  for (int k = tid; k < KDIM; k += 256) {
    float p = (float)counts[k] * (1.0f / 16384.0f);
    s += p * logf(p + 1e-10f);
  }
  sd[tid] = s;
  __syncthreads();
  for (int t = 128; t > 0; t >>= 1) {
    if (tid < t) sd[tid] += sd[tid + t];
    __syncthreads();
  }
  float S = sd[0];
  __syncthreads();
  float d = 0.0f;
  for (int t = tid; t < 1024; t += 256) d += dpart[t];
  sd[tid] = d;
  __syncthreads();
  for (int t = 128; t > 0; t >>= 1) {
    if (tid < t) sd[tid] += sd[tid + t];
    __syncthreads();
  }
  if (tid == 0) {
    out[DIFF_OFF] = sd[0] * (1.0f / 4194304.0f);
    out[PERP_OFF] = expf(-S);
  }
}

extern "C" void kernel_launch(void* const* d_in, const int* in_sizes, int n_in,
                              void* d_out, int out_size, void* d_ws, size_t ws_size,
                              hipStream_t stream) {
  const float* x = (const float*)d_in[0];   // [16,256,32,32]
  const float* e = (const float*)d_in[1];   // [256,8192] (leading 1,1 dims)
  float* out = (float*)d_out;
  char* ws = (char*)d_ws;

  unsigned long long* best = (unsigned long long*)(ws + 0);
  float* ee = (float*)(ws + 131072);
  float* Fv = (float*)(ws + 163840);
  int* ind = (int*)(ws + 229376);
  int* counts = (int*)(ws + 294912);
  float* dpart = (float*)(ws + 327680);

  hipMemsetAsync(best, 0xFF, 131072, stream);   // u64 max
  hipMemsetAsync(counts, 0, 32768, stream);

  k_ee<<<32, 256, 0, stream>>>(e, ee);
  k_ff<<<64, 256, 0, stream>>>(x, Fv);
  k_main<<<dim3(2, 128), 256, 0, stream>>>(x, e, Fv, ee, best);
  k_ind<<<64, 256, 0, stream>>>(best, ind, counts, out);
  k_out<<<1024, 256, 0, stream>>>(x, e, ind, out, dpart);
  k_perp<<<1, 256, 0, stream>>>(counts, dpart, out);
}

// Round 2
// 409.274 us; speedup vs baseline: 2.4475x; 2.4475x over previous
//
#include <hip/hip_runtime.h>

typedef _Float16 f16;
typedef f16 half8 __attribute__((ext_vector_type(8)));
typedef float f32x4 __attribute__((ext_vector_type(4)));
typedef unsigned long long u64;

#define NROWS 16384
#define KD 8192
#define DIFF_OFF 4194304
#define EIND_OFF 4194305
#define PERP_OFF 4210689
#define LCAP 8192

// ---- ws layout (bytes), total < 300KB (known-safe <= 331776) ----
// best u64[16384] @0 (131072) | Fv @131072 (65536) | ee @196608 (32768)
// counts @229376 (32768) | dpart @262144 (4096) | eemax @266240 | cnt @266244
// list u32[8192] @266248 (32768)
// ---- d_out scratch (bytes), dead before quantize written ----
// ehT fp16[8192][256] @0 (4MB) | m1 u64[16384*64] @4MB (8MB) | m2v f32 @12MB (4MB)

__device__ inline u64 packkey(float d, unsigned col) {
  unsigned u = __float_as_uint(d);
  u = (u & 0x80000000u) ? ~u : (u | 0x80000000u);
  return ((u64)u << 32) | col;
}
__device__ inline float unpackval(u64 k) {
  unsigned h = (unsigned)(k >> 32);
  h = (h & 0x80000000u) ? (h ^ 0x80000000u) : ~h;
  return __uint_as_float(h);
}
__device__ inline void merge2(u64& k1, float& v1, float& v2, u64 kb, float v1b, float v2b) {
  v2 = fminf(v2, v2b);
  if (kb < k1) { v2 = fminf(v2, v1); k1 = kb; v1 = v1b; }
  else v2 = fminf(v2, v1b);
}

// ||e_k||^2 replicating np.sum(e*e, axis=0) (sequential, no contraction) + max
__global__ __launch_bounds__(256) void k_ee(const float* __restrict__ e,
                                            float* __restrict__ ee,
                                            unsigned* __restrict__ eemax) {
#pragma clang fp contract(off)
  int k = blockIdx.x * 256 + threadIdx.x;
  float s = 0.0f;
  for (int c = 0; c < 256; ++c) { float v = e[(size_t)c * KD + k]; float sq = v * v; s = s + sq; }
  ee[k] = s;
  atomicMax(eemax, __float_as_uint(s));   // s > 0, uint order == float order
}

// ||f_n||^2 replicating numpy pairwise_sum (verified bit-exact round 1)
__global__ __launch_bounds__(256) void k_ff(const float* __restrict__ x,
                                            float* __restrict__ Fv) {
#pragma clang fp contract(off)
  int n = blockIdx.x * 256 + threadIdx.x;
  int b = n >> 10, hw = n & 1023;
  const float* px = x + ((size_t)b << 18) + hw;
  float sblk[2];
#pragma unroll
  for (int blk = 0; blk < 2; ++blk) {
    float r[8];
#pragma unroll
    for (int j = 0; j < 8; ++j) { float v = px[(size_t)(blk*128 + j) << 10]; r[j] = v * v; }
    for (int i = 8; i < 128; i += 8) {
#pragma unroll
      for (int j = 0; j < 8; ++j) {
        float v = px[(size_t)(blk*128 + i + j) << 10];
        float sq = v * v;
        r[j] = r[j] + sq;
      }
    }
    sblk[blk] = ((r[0]+r[1]) + (r[2]+r[3])) + ((r[4]+r[5]) + (r[6]+r[7]));
  }
  Fv[n] = sblk[0] + sblk[1];
}

// transpose e[256][8192] f32 -> ehT[8192][256] f16
__global__ __launch_bounds__(256) void k_tr(const float* __restrict__ e,
                                            f16* __restrict__ ehT) {
  __shared__ float sm[64][65];
  int tx = threadIdx.x & 63, ty = threadIdx.x >> 6;
  int k0 = blockIdx.x * 64, c0 = blockIdx.y * 64;
#pragma unroll
  for (int i = 0; i < 16; ++i) {
    int cl = i * 4 + ty;
    sm[cl][tx] = e[(size_t)(c0 + cl) * KD + k0 + tx];
  }
  __syncthreads();
#pragma unroll
  for (int i = 0; i < 16; ++i) {
    int kl = i * 4 + ty;
    ehT[(size_t)(k0 + kl) * 256 + c0 + tx] = (f16)sm[tx][kl];
  }
}

// fp16 MFMA approx-distance GEMM: per (row, 128-col chunk) -> top1 key + top2 val
__global__ __launch_bounds__(256) void k_gemm(const float* __restrict__ x,
                                              const f16* __restrict__ ehT,
                                              const float* __restrict__ eev,
                                              u64* __restrict__ m1,
                                              float* __restrict__ m2v) {
  __shared__ __align__(16) f16 As[128 * 64];   // [m][k], XOR-swizzled
  __shared__ __align__(16) f16 Bs[128 * 64];   // [n][k], XOR-swizzled
  __shared__ u64 redk[128][2];
  __shared__ float redv1[128][2];
  __shared__ float redv2[128][2];

  const int tid = threadIdx.x;
  const int lane = tid & 63;
  const int wave = tid >> 6;
  const int wm = wave >> 1, wn = wave & 1;
  const int row0 = blockIdx.y * 128;
  const int b = row0 >> 10, hw0 = row0 & 1023;
  const int n0 = blockIdx.x * 128;
  const int g = lane >> 4, l15 = lane & 15;

  f32x4 acc[4][4];
#pragma unroll
  for (int i = 0; i < 4; ++i)
#pragma unroll
    for (int j = 0; j < 4; ++j) acc[i][j] = (f32x4){0.f, 0.f, 0.f, 0.f};

  for (int kt = 0; kt < 4; ++kt) {
    const int k0 = kt * 64;
    {  // stage A: fp32 load + cvt + swizzled ds_write
      const int mq = tid & 31, co = tid >> 5;
      const int m0 = mq * 4;
      float4 v[8];
#pragma unroll
      for (int i = 0; i < 8; ++i)
        v[i] = *(const float4*)(x + (((size_t)(b * 256 + k0 + co * 8 + i)) << 10) + hw0 + m0);
#pragma unroll
      for (int mm = 0; mm < 4; ++mm) {
        const int m = m0 + mm;
        half8 h;
#pragma unroll
        for (int i = 0; i < 8; ++i) h[i] = (f16)(((const float*)&v[i])[mm]);
        *(half8*)((char*)As + ((m * 128 + co * 16) ^ ((m & 7) << 4))) = h;
      }
    }
#pragma unroll
    for (int p = 0; p < 4; ++p) {  // stage B (already fp16)
      int slot = tid + p * 256;
      int n = slot >> 3, s = slot & 7;
      uint4 q = *(const uint4*)((const char*)ehT + (size_t)(n0 + n) * 512 + k0 * 2 + s * 16);
      *(uint4*)((char*)Bs + ((n * 128 + s * 16) ^ ((n & 7) << 4))) = q;
    }
    __syncthreads();
#pragma unroll
    for (int s = 0; s < 2; ++s) {
      half8 af[4], bf[4];
#pragma unroll
      for (int mt = 0; mt < 4; ++mt) {
        int m = wm * 64 + mt * 16 + l15;
        af[mt] = *(const half8*)((const char*)As + ((m * 128 + s * 64 + g * 16) ^ ((m & 7) << 4)));
      }
#pragma unroll
      for (int nt = 0; nt < 4; ++nt) {
        int n = wn * 64 + nt * 16 + l15;
        bf[nt] = *(const half8*)((const char*)Bs + ((n * 128 + s * 64 + g * 16) ^ ((n & 7) << 4)));
      }
#pragma unroll
      for (int mt = 0; mt < 4; ++mt)
#pragma unroll
        for (int nt = 0; nt < 4; ++nt)
          acc[mt][nt] = __builtin_amdgcn_mfma_f32_16x16x32_f16(af[mt], bf[nt], acc[mt][nt], 0, 0, 0);
    }
    __syncthreads();
  }

  // epilogue: d' = ee - 2*dot (F dropped: constant per row); per-row top-2
  float eer[4]; unsigned coln[4];
#pragma unroll
  for (int nt = 0; nt < 4; ++nt) {
    coln[nt] = n0 + wn * 64 + nt * 16 + l15;
    eer[nt] = eev[coln[nt]];
  }
#pragma unroll
  for (int mt = 0; mt < 4; ++mt) {
#pragma unroll
    for (int r = 0; r < 4; ++r) {
      float d0 = fmaf(-2.f, acc[mt][0][r], eer[0]);
      u64 k1 = packkey(d0, coln[0]);
      float v1 = d0, v2 = __builtin_inff();
#pragma unroll
      for (int nt = 1; nt < 4; ++nt) {
        float dn = fmaf(-2.f, acc[mt][nt][r], eer[nt]);
        merge2(k1, v1, v2, packkey(dn, coln[nt]), dn, __builtin_inff());
      }
#pragma unroll
      for (int ml = 1; ml < 16; ml <<= 1) {
        u64 kb = __shfl_xor(k1, ml, 64);
        float v1b = __shfl_xor(v1, ml, 64);
        float v2b = __shfl_xor(v2, ml, 64);
        merge2(k1, v1, v2, kb, v1b, v2b);
      }
      if (l15 == 0) {
        int rl = wm * 64 + mt * 16 + g * 4 + r;
        redk[rl][wn] = k1; redv1[rl][wn] = v1; redv2[rl][wn] = v2;
      }
    }
  }
  __syncthreads();
  if (tid < 128) {
    u64 k1 = redk[tid][0]; float v1 = redv1[tid][0], v2 = redv2[tid][0];
    merge2(k1, v1, v2, redk[tid][1], redv1[tid][1], redv2[tid][1]);
    m1[(size_t)(row0 + tid) * 64 + blockIdx.x] = k1;
    m2v[(size_t)(row0 + tid) * 64 + blockIdx.x] = v2;
  }
}

// per-row selection + inline exact rescore of candidate cols (bit-exact chain)
__global__ __launch_bounds__(256) void k_sel(const float* __restrict__ x,
    const float* __restrict__ e, const u64* __restrict__ m1,
    const float* __restrict__ m2v, const float* __restrict__ Fv,
    const float* __restrict__ eev, const unsigned* __restrict__ eemax,
    u64* __restrict__ best, unsigned* __restrict__ cnt, unsigned* __restrict__ list) {
  const int row = (blockIdx.x << 2) + (threadIdx.x >> 6);
  const int lane = threadIdx.x & 63;
  u64 k1 = m1[(size_t)row * 64 + lane];
  float v2 = m2v[(size_t)row * 64 + lane];
  float v1 = unpackval(k1);
  u64 gk = k1;
#pragma unroll
  for (int m = 1; m < 64; m <<= 1) {
    u64 o = __shfl_xor(gk, m, 64);
    gk = (o < gk) ? o : gk;
  }
  float gval = unpackval(gk);
  float S = sqrtf(Fv[row] * __uint_as_float(*eemax));
  float eps = 0x1p-9f * S + 4e-4f;
  float thr = gval + 2.f * eps;
  const int b = row >> 10, hw = row & 1023;
  if (v2 <= thr) {  // >1 in-window col may hide in this chunk -> full rescore
    unsigned slot = atomicAdd(cnt, 1u);
    if (slot < LCAP) list[slot] = (unsigned)((row << 6) | lane);
    else {  // overflow fallback (correctness-preserving, ~never taken)
      for (int j = 0; j < 128; ++j) {
        int col = (lane << 7) + j;
        float a = 0.f;
        for (int c = 0; c < 256; ++c)
          a = fmaf(x[(((size_t)(b * 256 + c)) << 10) + hw], e[(size_t)c * KD + col], a);
        float t = fmaf(-2.f, a, Fv[row]);
        float d = t + eev[col];
        atomicMin(&best[row], packkey(d, (unsigned)col));
      }
    }
  }
  bool flag = (v1 <= thr);
  unsigned col = flag ? (unsigned)(k1 & 0xffffffffu) : (unsigned)(gk & 0xffffffffu);
  float a = 0.f;
  for (int c = 0; c < 256; ++c)
    a = fmaf(x[(((size_t)(b * 256 + c)) << 10) + hw], e[(size_t)c * KD + col], a);
  float t = fmaf(-2.f, a, Fv[row]);
  float d = t + eev[col];
  if (flag) atomicMin(&best[row], packkey(d, col));
}

// exact full-chunk rescore for flagged (row,chunk) tasks
__global__ __launch_bounds__(64) void k_chunk(const float* __restrict__ x,
    const float* __restrict__ e, const float* __restrict__ Fv,
    const float* __restrict__ eev, const unsigned* __restrict__ cnt,
    const unsigned* __restrict__ list, u64* __restrict__ best) {
  unsigned n = *cnt; if (n > LCAP) n = LCAP;
  for (unsigned t = blockIdx.x; t < n; t += gridDim.x) {
    unsigned v = list[t];
    int row = v >> 6, ch = v & 63;
    int b = row >> 10, hw = row & 1023;
#pragma unroll
    for (int hf = 0; hf < 2; ++hf) {
      int col = (ch << 7) + (int)threadIdx.x + hf * 64;
      float a = 0.f;
      for (int c = 0; c < 256; ++c)
        a = fmaf(x[(((size_t)(b * 256 + c)) << 10) + hw], e[(size_t)c * KD + col], a);
      float t2 = fmaf(-2.f, a, Fv[row]);
      float d = t2 + eev[col];
      atomicMin(&best[row], packkey(d, (unsigned)col));
    }
  }
}

__global__ __launch_bounds__(256) void k_ind(const u64* __restrict__ best,
                                             int* __restrict__ counts,
                                             float* __restrict__ out) {
  int n = blockIdx.x * 256 + threadIdx.x;
  unsigned idx = (unsigned)(best[n] & 0xffffffffu);
  out[EIND_OFF + n] = (float)idx;
  atomicAdd(&counts[idx], 1);
}

__global__ __launch_bounds__(256) void k_out(const float* __restrict__ x,
                                             const float* __restrict__ e,
                                             float* __restrict__ out,
                                             float* __restrict__ dpart) {
  __shared__ float sd[256];
  int tid = threadIdx.x;
  float local = 0.0f;
  for (size_t i = (size_t)blockIdx.x * 256 + tid; i < 4194304ull; i += (size_t)gridDim.x * 256) {
    int hw = (int)(i & 1023);
    int c = (int)((i >> 10) & 255);
    int bb = (int)(i >> 18);
    int n = (bb << 10) + hw;
    int idx = (int)out[EIND_OFF + n];
    float xv = x[i];
    float q = e[(size_t)c * KD + idx];
    float qd = q - xv;
    out[i] = xv + qd;
    local += qd * qd;
  }
  sd[tid] = local;
  __syncthreads();
  for (int s = 128; s > 0; s >>= 1) {
    if (tid < s) sd[tid] += sd[tid + s];
    __syncthreads();
  }
  if (tid == 0) dpart[blockIdx.x] = sd[0];
}

__global__ __launch_bounds__(256) void k_perp(const int* __restrict__ counts,
                                              const float* __restrict__ dpart,
                                              float* __restrict__ out) {
  __shared__ float sd[256];
  int tid = threadIdx.x;
  float s = 0.0f;
  for (int k = tid; k < KD; k += 256) {
    float p = (float)counts[k] * (1.0f / 16384.0f);
    s += p * logf(p + 1e-10f);
  }
  sd[tid] = s;
  __syncthreads();
  for (int t = 128; t > 0; t >>= 1) {
    if (tid < t) sd[tid] += sd[tid + t];
    __syncthreads();
  }
  float S = sd[0];
  __syncthreads();
  float d = 0.0f;
  for (int t = tid; t < 1024; t += 256) d += dpart[t];
  sd[tid] = d;
  __syncthreads();
  for (int t = 128; t > 0; t >>= 1) {
    if (tid < t) sd[tid] += sd[tid + t];
    __syncthreads();
  }
  if (tid == 0) {
    out[DIFF_OFF] = sd[0] * (1.0f / 4194304.0f);
    out[PERP_OFF] = expf(-S);
  }
}

extern "C" void kernel_launch(void* const* d_in, const int* in_sizes, int n_in,
                              void* d_out, int out_size, void* d_ws, size_t ws_size,
                              hipStream_t stream) {
  const float* x = (const float*)d_in[0];   // [16,256,32,32]
  const float* e = (const float*)d_in[1];   // [256,8192]
  float* out = (float*)d_out;
  char* dc = (char*)d_out;
  char* ws = (char*)d_ws;

  u64* best = (u64*)(ws);
  float* Fv = (float*)(ws + 131072);
  float* eev = (float*)(ws + 196608);
  int* counts = (int*)(ws + 229376);
  float* dpart = (float*)(ws + 262144);
  unsigned* eemax = (unsigned*)(ws + 266240);
  unsigned* cnt = (unsigned*)(ws + 266244);
  unsigned* list = (unsigned*)(ws + 266248);

  f16* ehT = (f16*)(dc);
  u64* m1 = (u64*)(dc + (4u << 20));
  float* m2v = (float*)(dc + (12u << 20));

  hipMemsetAsync(best, 0xFF, 131072, stream);
  hipMemsetAsync(counts, 0, 36872, stream);   // counts + dpart + eemax + cnt

  k_ee<<<32, 256, 0, stream>>>(e, eev, eemax);
  k_ff<<<64, 256, 0, stream>>>(x, Fv);
  k_tr<<<dim3(128, 4), 256, 0, stream>>>(e, ehT);
  k_gemm<<<dim3(64, 128), 256, 0, stream>>>(x, ehT, eev, m1, m2v);
  k_sel<<<4096, 256, 0, stream>>>(x, e, m1, m2v, Fv, eev, eemax, best, cnt, list);
  k_chunk<<<512, 64, 0, stream>>>(x, e, Fv, eev, cnt, list, best);
  k_ind<<<64, 256, 0, stream>>>(best, counts, out);
  k_out<<<1024, 256, 0, stream>>>(x, e, out, dpart);
  k_perp<<<1, 256, 0, stream>>>(counts, dpart, out);
}